// Round 3
// baseline (312.015 us; speedup 1.0000x reference)
//
#include <hip/hip_runtime.h>
#include <math.h>

// Problem constants (B=8, F=32 -> 256 frames of 224x224x3 f32)
#define NFRAMES 256
#define NH 224
#define NW 224
#define NPIX (NH * NW)            // 50176
#define NOISE_LEN 766             // 3*L - 2
#define WIN_LEN 511               // 2*L - 1

#define PPT 4                               // pixels per thread (224 % 4 == 0 -> never crosses rows)
#define TPB 256
#define PIX_PER_BLOCK (TPB * PPT)           // 1024
#define BLOCKS_PER_FRAME (NPIX / PIX_PER_BLOCK)  // 49
#define GROUPS_PER_ROW (NW / PPT)           // 56
#define FRAME_FLOATS (NPIX * 3)             // 150528
#define MAXIDX (NFRAMES * FRAME_FLOATS - 3) // only float-index that can overrun a dwordx4 by 4B

typedef float f4 __attribute__((ext_vector_type(4), aligned(4)));

// ---------------------------------------------------------------------------
// Kernel 1: one block per frame. Wave j computes the 511-tap convolution for
// noise row j at output position b (8 taps/lane, f64, 64-lane shuffle reduce).
// Window norm S via closed-form geometric series. Thread 0 composes M in f64.
// ---------------------------------------------------------------------------
__global__ __launch_bounds__(256) void build_mats_v2(
    const float* __restrict__ noise,   // (4, 766)
    const float* __restrict__ basis,   // (4, 3, 3)
    float* __restrict__ Mout) {        // (256, 9)
  const int b = blockIdx.x;
  const int t = threadIdx.x;
  const int j = t >> 6;
  const int lane = t & 63;

  __shared__ double wsh[WIN_LEN];
  __shared__ double vsh[4];

  for (int k = t; k < WIN_LEN; k += 256) {
    int e = 255 - abs(k - 255);
    wsh[k] = pow(1.1, (double)e);
  }
  __syncthreads();

  const double S = (pow(1.1, 255.0) - 1.0) * 10.0 + (pow(1.1, 256.0) - 1.0) * 10.0;

  const float* row = noise + j * NOISE_LEN + b;
  const int k0 = lane * 8;
  double acc = 0.0;
  #pragma unroll
  for (int i = 0; i < 8; ++i) {
    const int k = k0 + i;
    if (k < WIN_LEN) acc = fma((double)row[k], wsh[k], acc);
  }
  #pragma unroll
  for (int off = 32; off > 0; off >>= 1) acc += __shfl_down(acc, off, 64);
  if (lane == 0) {
    const double v = acc / S;
    vsh[j] = v > 0.0 ? v : 0.0;
  }
  __syncthreads();

  if (t == 0) {
    const double wv0 = vsh[0], wv1 = vsh[1], wv2 = vsh[2], wv3 = vsh[3];
    const double swv = wv0 + wv1 + wv2 + wv3;
    double warp[9];
    #pragma unroll
    for (int e = 0; e < 9; ++e) {
      warp[e] = wv0 * (double)basis[0 * 9 + e] + wv1 * (double)basis[1 * 9 + e] +
                wv2 * (double)basis[2 * 9 + e] + wv3 * (double)basis[3 * 9 + e];
    }
    warp[0] += 4.0 - swv;
    warp[4] += 4.0 - swv;
    warp[8] += 4.0 - swv;

    const double W1 = (double)(NW - 1);
    const double H1 = (double)(NH - 1);
    double T[9];
    #pragma unroll
    for (int c = 0; c < 3; ++c) {
      T[0 * 3 + c] = W1 * warp[0 * 3 + c] + 0.5 * W1 * warp[2 * 3 + c];
      T[1 * 3 + c] = H1 * warp[1 * 3 + c] + 0.5 * H1 * warp[2 * 3 + c];
      T[2 * 3 + c] = warp[2 * 3 + c];
    }
    float* Mo = Mout + b * 9;
    #pragma unroll
    for (int r = 0; r < 3; ++r) {
      Mo[r * 3 + 0] = (float)(T[r * 3 + 0] / W1);
      Mo[r * 3 + 1] = (float)(T[r * 3 + 1] / H1);
      Mo[r * 3 + 2] = (float)(-0.5 * T[r * 3 + 0] - 0.5 * T[r * 3 + 1] + T[r * 3 + 2]);
    }
  }
}

// One dwordx4 per corner (4B-aligned wide load; HW needs only dword alignment).
// GUARD handles the single index (last pixel of last frame) that would read
// 4B past the tensor: shift the load down one float and select.
template <bool GUARD>
__device__ __forceinline__ void gather3(const float* __restrict__ xb, int idx,
                                        float& c0, float& c1, float& c2) {
  if (GUARD) {
    const bool sh = (idx == MAXIDX);
    const f4 q = *(const f4*)(xb + (sh ? idx - 1 : idx));
    c0 = sh ? q.y : q.x;
    c1 = sh ? q.z : q.y;
    c2 = sh ? q.w : q.z;
  } else {
    const f4 q = *(const f4*)(xb + idx);
    c0 = q.x; c1 = q.y; c2 = q.z;
  }
}

template <bool GUARD>
__device__ __forceinline__ void do_block(
    const float* __restrict__ x, const float* __restrict__ M,
    float* __restrict__ out, int l, int bin) {
  const float* Mp = M + l * 9;   // uniform -> scalar loads
  const float m00 = Mp[0], m01 = Mp[1], m02 = Mp[2];
  const float m10 = Mp[3], m11 = Mp[4], m12 = Mp[5];
  const float m20 = Mp[6], m21 = Mp[7], m22 = Mp[8];

  const int g = bin * TPB + (int)threadIdx.x;   // pixel-group within frame
  const int r = g / GROUPS_PER_ROW;
  const int c0i = (g - r * GROUPS_PER_ROW) * PPT;
  const float rf = (float)r;
  const int frame_off = l * FRAME_FLOATS;

  float o[PPT * 3];
  #pragma unroll
  for (int i = 0; i < PPT; ++i) {
    const float cf = (float)(c0i + i);
    const float fx = fmaf(m00, cf, fmaf(m01, rf, m02));
    const float fy = fmaf(m10, cf, fmaf(m11, rf, m12));
    const float fz = fmaf(m20, cf, fmaf(m21, rf, m22));
    const float inv = __builtin_amdgcn_rcpf(fz);
    const float xs = fx * inv;
    const float ys = fy * inv;

    const float x0f = floorf(xs), y0f = floorf(ys);
    const float wx = xs - x0f, wy = ys - y0f;
    const float x1f = x0f + 1.0f, y1f = y0f + 1.0f;

    const float vx0 = (x0f >= 0.0f && x0f <= (float)(NW - 1)) ? 1.0f : 0.0f;
    const float vx1 = (x1f >= 0.0f && x1f <= (float)(NW - 1)) ? 1.0f : 0.0f;
    const float vy0 = (y0f >= 0.0f && y0f <= (float)(NH - 1)) ? 1.0f : 0.0f;
    const float vy1 = (y1f >= 0.0f && y1f <= (float)(NH - 1)) ? 1.0f : 0.0f;

    const int xi0 = (int)fminf(fmaxf(x0f, 0.0f), (float)(NW - 1));
    const int xi1 = (int)fminf(fmaxf(x1f, 0.0f), (float)(NW - 1));
    const int yi0 = (int)fminf(fmaxf(y0f, 0.0f), (float)(NH - 1));
    const int yi1 = (int)fminf(fmaxf(y1f, 0.0f), (float)(NH - 1));

    const int i00 = frame_off + (yi0 * NW + xi0) * 3;
    const int i01 = frame_off + (yi0 * NW + xi1) * 3;
    const int i10 = frame_off + (yi1 * NW + xi0) * 3;
    const int i11 = frame_off + (yi1 * NW + xi1) * 3;

    float a0, a1, a2, b0, b1, b2, d0, d1, d2, e0, e1, e2;
    gather3<GUARD>(x, i00, a0, a1, a2);
    gather3<GUARD>(x, i01, b0, b1, b2);
    gather3<GUARD>(x, i10, d0, d1, d2);
    gather3<GUARD>(x, i11, e0, e1, e2);

    const float w00 = (1.0f - wy) * (1.0f - wx) * vy0 * vx0;
    const float w01 = (1.0f - wy) * wx * vy0 * vx1;
    const float w10 = wy * (1.0f - wx) * vy1 * vx0;
    const float w11 = wy * wx * vy1 * vx1;

    o[i * 3 + 0] = w00 * a0 + w01 * b0 + w10 * d0 + w11 * e0;
    o[i * 3 + 1] = w00 * a1 + w01 * b1 + w10 * d1 + w11 * e1;
    o[i * 3 + 2] = w00 * a2 + w01 * b2 + w10 * d2 + w11 * e2;
  }

  // 12 contiguous floats, 48B-aligned -> 3 nontemporal dwordx4 stores
  float* op = out + (size_t)frame_off + (size_t)g * (PPT * 3);
  #pragma unroll
  for (int v = 0; v < 3; ++v) {
    f4 q;
    q.x = o[v * 4 + 0]; q.y = o[v * 4 + 1]; q.z = o[v * 4 + 2]; q.w = o[v * 4 + 3];
    __builtin_nontemporal_store(q, (f4*)(op + v * 4));
  }
}

__global__ __launch_bounds__(256) void warp_bilinear_v3(
    const float* __restrict__ x,     // (256, 224, 224, 3)
    const float* __restrict__ M,     // (256, 9)
    float* __restrict__ out) {       // (256, 224, 224, 3)
  const int bid = blockIdx.x;
  const int l = bid / BLOCKS_PER_FRAME;              // frame (block-uniform)
  const int bin = bid - l * BLOCKS_PER_FRAME;        // block within frame

  if (l == NFRAMES - 1) {
    do_block<true>(x, M, out, l, bin);    // guard the 4B tensor-end overrun
  } else {
    do_block<false>(x, M, out, l, bin);
  }
}

extern "C" void kernel_launch(void* const* d_in, const int* in_sizes, int n_in,
                              void* d_out, int out_size, void* d_ws, size_t ws_size,
                              hipStream_t stream) {
  (void)in_sizes; (void)n_in; (void)out_size; (void)ws_size;
  const float* x     = (const float*)d_in[0];   // (8,32,224,224,3) f32
  const float* noise = (const float*)d_in[1];   // (4,766) f32
  const float* basis = (const float*)d_in[2];   // (4,3,3) f32
  float* out  = (float*)d_out;
  float* Mbuf = (float*)d_ws;                   // 256*9 floats scratch

  build_mats_v2<<<NFRAMES, 256, 0, stream>>>(noise, basis, Mbuf);
  warp_bilinear_v3<<<NFRAMES * BLOCKS_PER_FRAME, 256, 0, stream>>>(x, Mbuf, out);
}